// Round 1
// baseline (197.497 us; speedup 1.0000x reference)
//
#include <hip/hip_runtime.h>

#define NEGF (-1e30f)

__device__ __forceinline__ float lae3(float a0, float a1, float a2) {
    float m = fmaxf(fmaxf(a0, a1), a2);
    return m + __logf(__expf(a0 - m) + __expf(a1 - m) + __expf(a2 - m));
}

__device__ __forceinline__ float lae2(float a0, float a1) {
    float m = fmaxf(a0, a1);
    return m + __logf(__expf(a0 - m) + __expf(a1 - m));
}

// One block per batch row. 256 threads: thread s owns extended-label state s;
// thread 0 additionally owns state 256. Threads 0..C-1 stage the logp row for
// step t into LDS (double-buffered), prefetching raw y_pred rows 2 steps ahead
// in registers to hide HBM/L2 latency.
__global__ __launch_bounds__(256, 1) void ctc_alpha_kernel(
        const int* __restrict__ y_true, const float* __restrict__ y_pred,
        float* __restrict__ out, int T, int C, int U) {
    const int b   = blockIdx.x;
    const int tid = threadIdx.x;
    const int blank = C - 1;

    __shared__ float alpha[257];
    __shared__ float rowbuf[2][128];
    __shared__ int   labels[128];

    if (tid < U) labels[tid] = y_true[b * U + tid];
    __syncthreads();

    const int s = tid;            // state 0..255
    int  cls;
    bool skip;
    if (s & 1) {
        int li = (s - 1) >> 1;
        cls  = labels[li];
        skip = (s >= 3) && (cls != labels[li - 1]);
    } else {
        cls  = blank;
        skip = false;
    }
    // thread 0's extra state s=256: class=blank, skip=false

    const float* yp = y_pred + (size_t)b * T * C;

    // --- t = 0: stage logp row 0, init alpha ---
    if (tid < C) rowbuf[0][tid] = __logf(yp[tid] + 1e-7f);
    __syncthreads();
    float init = NEGF;
    if (s == 0)      init = rowbuf[0][blank];
    else if (s == 1) init = rowbuf[0][cls];
    alpha[s] = init;
    if (tid == 0) alpha[256] = NEGF;

    // 2-deep prefetch of raw y_pred rows
    float r0 = 0.f, r1 = 0.f;
    if (tid < C) {
        r0 = yp[(size_t)C + tid];                      // row 1
        if (T > 2) r1 = yp[(size_t)2 * C + tid];       // row 2
    }
    __syncthreads();

    for (int t = 1; t < T; t += 2) {
        // ---------- step t (consumes r0) ----------
        {
            if (tid < C) rowbuf[t & 1][tid] = __logf(r0 + 1e-7f);
            float a0 = alpha[s];
            float a1 = (s >= 1) ? alpha[s - 1] : NEGF;
            float a2 = skip ? alpha[s - 2] : NEGF;
            float b0 = NEGF, b1 = NEGF;
            if (tid == 0) { b0 = alpha[256]; b1 = alpha[255]; }
            if (tid < C && t + 2 < T) r0 = yp[(size_t)(t + 2) * C + tid];
            __syncthreads();
            float lp = rowbuf[t & 1][cls];
            alpha[s] = lae3(a0, a1, a2) + lp;
            if (tid == 0) alpha[256] = lae2(b0, b1) + rowbuf[t & 1][blank];
            __syncthreads();
        }
        // ---------- step t+1 (consumes r1) ----------
        if (t + 1 < T) {
            int tt = t + 1;
            if (tid < C) rowbuf[tt & 1][tid] = __logf(r1 + 1e-7f);
            float a0 = alpha[s];
            float a1 = (s >= 1) ? alpha[s - 1] : NEGF;
            float a2 = skip ? alpha[s - 2] : NEGF;
            float b0 = NEGF, b1 = NEGF;
            if (tid == 0) { b0 = alpha[256]; b1 = alpha[255]; }
            if (tid < C && tt + 2 < T) r1 = yp[(size_t)(tt + 2) * C + tid];
            __syncthreads();
            float lp = rowbuf[tt & 1][cls];
            alpha[s] = lae3(a0, a1, a2) + lp;
            if (tid == 0) alpha[256] = lae2(b0, b1) + rowbuf[tt & 1][blank];
            __syncthreads();
        }
    }

    if (tid == 0) {
        out[b] = -lae2(alpha[255], alpha[256]);
    }
}

extern "C" void kernel_launch(void* const* d_in, const int* in_sizes, int n_in,
                              void* d_out, int out_size, void* d_ws, size_t ws_size,
                              hipStream_t stream) {
    const int*   y_true = (const int*)d_in[0];
    const float* y_pred = (const float*)d_in[1];
    float*       out    = (float*)d_out;

    const int B = out_size;                 // 256
    const int U = in_sizes[0] / B;          // 128
    const int C = 128;                      // num classes (fixed by problem)
    const int T = in_sizes[1] / (B * C);    // 512

    ctc_alpha_kernel<<<B, 256, 0, stream>>>(y_true, y_pred, out, T, C, U);
}

// Round 2
// 91.466 us; speedup vs baseline: 2.1592x; 2.1592x over previous
//
#include <hip/hip_runtime.h>

// CTC loss, Keras convention: blank = C-1, logp = log(y_pred + 1e-7),
// full-length inputs/labels. One 64-lane wave per batch row.
//
// Linear-domain scaled forward recursion (Rabiner scaling):
//   u stores exp(alpha - O), O a wave-uniform running log-offset.
//   Per step: u'_s = (u_s + u_{s-1} + skip_s * u_{s-2}) * p_s / p_blank
//   (blank states: * p_blank / p_blank == exact no-op, no multiply)
//   O += log(p_blank + eps) each step; wave-max renorm every 8 steps.
//
// Lane t owns states 4t..4t+3 in regs u0..u3; u4 = state 256 (lane 63).
// Only cross-lane dependency per step: prev lane's u3 (one __shfl_up).
// No __syncthreads anywhere in the T loop -> prefetched global loads are
// never drained by a barrier; compiler waits per-use only.

__device__ __forceinline__ float fast_rcp(float x) {
    return __builtin_amdgcn_rcpf(x);
}

__global__ __launch_bounds__(64, 1) void ctc_linear_kernel(
        const int* __restrict__ y_true, const float* __restrict__ y_pred,
        float* __restrict__ out, int T, int C, int U) {
    const int b    = blockIdx.x;
    const int lane = threadIdx.x;          // 0..63
    const int blank = C - 1;
    const float EPS = 1e-7f;

    const float* yp  = y_pred + (size_t)b * T * C;
    const int*   lab = y_true + (size_t)b * U;

    // this lane's two label states (s = 4*lane+1 and 4*lane+3)
    const int c1 = lab[2 * lane];
    const int c3 = lab[2 * lane + 1];
    const int cp = (lane == 0) ? -1 : lab[2 * lane - 1];
    const bool skip1 = (lane > 0) && (c1 != cp);   // s>=3 and label != label-1
    const bool skip3 = (c3 != c1);

    // ---- t = 0 init: alpha0[0] = lp[blank], alpha0[1] = lp[label0] ----
    float u0 = 0.f, u1 = 0.f, u2 = 0.f, u3 = 0.f, u4 = 0.f;
    if (lane == 0) {
        u0 = yp[blank] + EPS;
        u1 = yp[c1] + EPS;
    }
    float O = 0.f;   // wave-uniform log offset (identical on all lanes)

    // ---- prefetch probability triples for steps 1..8 ----
    float pfb[8], pf1[8], pf3[8];
#pragma unroll
    for (int k = 0; k < 8; ++k) {
        int t = 1 + k; if (t > T - 1) t = T - 1;
        const float* row = yp + (size_t)t * C;
        pfb[k] = row[blank];
        pf1[k] = row[c1];
        pf3[k] = row[c3];
    }

    const int NCH = (T - 1) / 8;   // full 8-step chunks (63 for T=512)

    for (int c = 0; c < NCH; ++c) {
#pragma unroll
        for (int k = 0; k < 8; ++k) {
            const float PB = pfb[k], P1 = pf1[k], P3 = pf3[k];
            // rolling prefetch: refill slot k for step (8c+9+k)
            int tn = 8 * c + 9 + k; if (tn > T - 1) tn = T - 1;
            const float* row = yp + (size_t)tn * C;
            pfb[k] = row[blank];
            pf1[k] = row[c1];
            pf3[k] = row[c3];

            // ---- one CTC step ----
            const float pbe = PB + EPS;
            const float rpb = fast_rcp(pbe);
            const float q1  = (P1 + EPS) * rpb;
            const float q3  = (P3 + EPS) * rpb;

            float n3 = __shfl_up(u3, 1);          // prev lane's state 4t-1
            n3 = (lane == 0) ? 0.f : n3;

            const float t1 = u1 + u0 + (skip1 ? n3 : 0.f);
            const float t3 = u3 + u2 + (skip3 ? u1 : 0.f);
            u4 = u4 + u3;          // state 256: * pb/pb == 1
            u3 = t3 * q3;
            u2 = u2 + u1;          // blank: no multiply
            u1 = t1 * q1;
            u0 = u0 + n3;          // blank: no multiply
            O += __logf(pbe);
        }
        // ---- wave-wide max renorm (every 8 steps) ----
        float m = fmaxf(fmaxf(u0, u1), fmaxf(u2, fmaxf(u3, u4)));
#pragma unroll
        for (int off = 32; off >= 1; off >>= 1)
            m = fmaxf(m, __shfl_xor(m, off));
        const float rm = fast_rcp(m);
        u0 *= rm; u1 *= rm; u2 *= rm; u3 *= rm; u4 *= rm;
        O += __logf(m);
    }

    // ---- tail steps: t = 8*NCH+1 .. T-1 (7 for T=512) ----
    const int rem = (T - 1) - 8 * NCH;
#pragma unroll
    for (int k = 0; k < 8; ++k) {
        if (k < rem) {
            const float pbe = pfb[k] + EPS;
            const float rpb = fast_rcp(pbe);
            const float q1  = (pf1[k] + EPS) * rpb;
            const float q3  = (pf3[k] + EPS) * rpb;

            float n3 = __shfl_up(u3, 1);
            n3 = (lane == 0) ? 0.f : n3;

            const float t1 = u1 + u0 + (skip1 ? n3 : 0.f);
            const float t3 = u3 + u2 + (skip3 ? u1 : 0.f);
            u4 = u4 + u3;
            u3 = t3 * q3;
            u2 = u2 + u1;
            u1 = t1 * q1;
            u0 = u0 + n3;
            O += __logf(pbe);
        }
    }

    // loss = -logaddexp(alpha[S-1], alpha[S-2]) = -(O + log(u255 + u256))
    if (lane == 63) {
        out[b] = -(O + __logf(u3 + u4));
    }
}

extern "C" void kernel_launch(void* const* d_in, const int* in_sizes, int n_in,
                              void* d_out, int out_size, void* d_ws, size_t ws_size,
                              hipStream_t stream) {
    const int*   y_true = (const int*)d_in[0];
    const float* y_pred = (const float*)d_in[1];
    float*       out    = (float*)d_out;

    const int B = out_size;                 // 256
    const int U = in_sizes[0] / B;          // 128
    const int C = 128;                      // classes incl. blank
    const int T = in_sizes[1] / (B * C);    // 512

    ctc_linear_kernel<<<B, 64, 0, stream>>>(y_true, y_pred, out, T, C, U);
}

// Round 3
// 68.780 us; speedup vs baseline: 2.8714x; 1.3298x over previous
//
#include <hip/hip_runtime.h>

#define EPSF 1e-7f

// DPP move with old=0: invalid source lanes produce 0. ctrl must be a literal.
#define DPPF0(x, ctrl) \
    __int_as_float(__builtin_amdgcn_update_dpp(0, __float_as_int(x), ctrl, 0xF, 0xF, false))

__device__ __forceinline__ float f_rcp(float x) { return __builtin_amdgcn_rcpf(x); }

// whole-wave shift right by 1 (lane l gets lane l-1; lane 0 gets 0) — VALU pipe
__device__ __forceinline__ float wave_shr1_f(float x) { return DPPF0(x, 0x138); }

// classic gfx9 wave64 max-reduce: row_shr 1,2,4,8 + row_bcast15 + row_bcast31,
// then broadcast lane 63 via readlane. Entirely VALU/SALU — no DS.
__device__ __forceinline__ float wave_max64(float x) {
    x = fmaxf(x, DPPF0(x, 0x111));   // row_shr:1
    x = fmaxf(x, DPPF0(x, 0x112));   // row_shr:2
    x = fmaxf(x, DPPF0(x, 0x114));   // row_shr:4
    x = fmaxf(x, DPPF0(x, 0x118));   // row_shr:8
    x = fmaxf(x, DPPF0(x, 0x142));   // row_bcast:15
    x = fmaxf(x, DPPF0(x, 0x143));   // row_bcast:31
    return __int_as_float(__builtin_amdgcn_readlane(__float_as_int(x), 63));
}

// One 64-lane wave per batch row. Lane l owns extended states 4l..4l+3 in
// u0..u3; u4 = state 256 (valid on lane 63). Linear-domain Rabiner-scaled
// recursion; blank states need no multiply. Renorm every 8 steps with a
// 2-step delayed apply so the DPP reduce overlaps scan steps.
__global__ __launch_bounds__(64, 1) void ctc_scan_kernel(
        const int* __restrict__ y_true, const float* __restrict__ y_pred,
        float* __restrict__ out, int T, int C, int U) {
    const int b    = blockIdx.x;
    const int lane = threadIdx.x;
    const int blank = C - 1;
    const float* __restrict__ yp = y_pred + (size_t)b * T * C;

    // labels: lane l needs lab[2l], lab[2l+1]; prev-lane label via DPP
    const int2 lc = ((const int2*)(y_true + (size_t)b * U))[lane];
    const int c1 = lc.x, c3 = lc.y;
    const int cp = __builtin_amdgcn_update_dpp(0, c3, 0x138, 0xF, 0xF, false);
    const float m1 = (lane > 0 && c1 != cp) ? 1.f : 0.f;
    const float m3 = (c3 != c1) ? 1.f : 0.f;

    float u0, u1, u2 = 0.f, u3 = 0.f, u4 = 0.f;
    {
        const float pvb = yp[blank];
        const float pv1 = yp[c1];
        u0 = (lane == 0) ? pvb + EPSF : 0.f;
        u1 = (lane == 0) ? pv1 + EPSF : 0.f;
    }
    float O = 0.f;                 // wave-uniform log offset
    const int Tm1 = T - 1;

    // 16-deep rolling prefetch of (blank, c1, c3) probabilities
    float pb[16], p1[16], p3[16];
#pragma unroll
    for (int k = 0; k < 16; ++k) {
        int t = 1 + k; t = t > Tm1 ? Tm1 : t;
        const float* row = yp + (size_t)t * C;
        pb[k] = row[blank]; p1[k] = row[c1]; p3[k] = row[c3];
    }

    float m_carry = 1.0f, m_snap = 1.0f;

    auto do_step = [&](float PB, float P1, float P3) {
        const float pbe = PB + EPSF;
        const float rpb = f_rcp(pbe);
        const float q1  = (P1 + EPSF) * rpb;
        const float q3  = (P3 + EPSF) * rpb;
        const float n3  = wave_shr1_f(u3);          // prev lane's state 4l-1
        const float t1  = fmaf(m1, n3, u0 + u1);
        const float t3  = fmaf(m3, u1, u2 + u3);
        u4 = u4 + u3;          // state 256 (blank): no multiply
        u3 = t3 * q3;
        u2 = u2 + u1;          // blank
        u1 = t1 * q1;
        u0 = u0 + n3;          // blank
        O += __logf(pbe);
    };
    auto apply = [&](float ms) {   // exactness-preserving rescale
        const float rm = f_rcp(ms);
        u0 *= rm; u1 *= rm; u2 *= rm; u3 *= rm; u4 *= rm;
        O += __logf(ms);
    };
    auto snap = [&]() -> float {
        return wave_max64(fmaxf(fmaxf(u0, u1), fmaxf(u2, fmaxf(u3, u4))));
    };

    const int NB = Tm1 / 16;       // full 16-step blocks
    for (int blk = 0; blk < NB; ++blk) {
        const int tb = 17 + 16 * blk;   // refill target for slot 0
#pragma unroll
        for (int k = 0; k < 16; ++k) {
            const float PB = pb[k], P1 = p1[k], P3 = p3[k];
            int tn = tb + k; tn = tn > Tm1 ? Tm1 : tn;
            const float* row = yp + (size_t)tn * C;
            pb[k] = row[blank]; p1[k] = row[c1]; p3[k] = row[c3];
            do_step(PB, P1, P3);
            if (k == 1)  apply(m_carry);     // from prev block's k==15 snapshot
            if (k == 7)  m_snap = snap();    // applied at k==9
            if (k == 9)  apply(m_snap);
            if (k == 15) m_carry = snap();   // applied next block k==1
        }
    }

    // tail: rem = (T-1) % 16 steps (15 for T=512), slots already prefetched
    const int rem = Tm1 - 16 * NB;
#pragma unroll
    for (int k = 0; k < 16; ++k) {
        if (k < rem) {
            do_step(pb[k], p1[k], p3[k]);
            if (k == 1) apply(m_carry);
            if (k == 7) m_snap = snap();
            if (k == 9) apply(m_snap);
        }
    }

    // loss = -(O + log(u[255] + u[256])), states live on lane 63
    if (lane == 63) out[b] = -(O + __logf(u3 + u4));
}

extern "C" void kernel_launch(void* const* d_in, const int* in_sizes, int n_in,
                              void* d_out, int out_size, void* d_ws, size_t ws_size,
                              hipStream_t stream) {
    const int*   y_true = (const int*)d_in[0];
    const float* y_pred = (const float*)d_in[1];
    float*       out    = (float*)d_out;

    const int B = out_size;                 // 256
    const int U = in_sizes[0] / B;          // 128
    const int C = 128;                      // classes incl. blank
    const int T = in_sizes[1] / (B * C);    // 512

    ctc_scan_kernel<<<B, 64, 0, stream>>>(y_true, y_pred, out, T, C, U);
}

// Round 4
// 45.110 us; speedup vs baseline: 4.3781x; 1.5247x over previous
//
#include <hip/hip_runtime.h>

#define EPSF 1e-7f

// ---- DPP helpers (all cross-lane on the VALU pipe, no DS) ----
#define DPPF0(x, ctrl) \
    __int_as_float(__builtin_amdgcn_update_dpp(0, __float_as_int(x), ctrl, 0xF, 0xF, false))

__device__ __forceinline__ float f_rcp(float x) { return __builtin_amdgcn_rcpf(x); }
__device__ __forceinline__ float wave_shr1_f(float x) { return DPPF0(x, 0x138); }

__device__ __forceinline__ float wave_max64(float x) {
    x = fmaxf(x, DPPF0(x, 0x111));   // row_shr:1
    x = fmaxf(x, DPPF0(x, 0x112));   // row_shr:2
    x = fmaxf(x, DPPF0(x, 0x114));   // row_shr:4
    x = fmaxf(x, DPPF0(x, 0x118));   // row_shr:8
    x = fmaxf(x, DPPF0(x, 0x142));   // row_bcast:15
    x = fmaxf(x, DPPF0(x, 0x143));   // row_bcast:31
    return __int_as_float(__builtin_amdgcn_readlane(__float_as_int(x), 63));
}

// ---- explicit load pipeline (compiler cannot defeat it) ----
#define SB0() __builtin_amdgcn_sched_barrier(0)
#define WAITV(N) do { asm volatile("s_waitcnt vmcnt(" #N ")" ::: "memory"); SB0(); } while (0)

// one dword gather: wave-uniform row base (SGPR pair) + per-lane class voffset
// + static row-within-window immediate. No per-step address arithmetic.
#define ISS(dst, voff, IMM) \
    asm volatile("global_load_dword %0, %1, %2 offset:" #IMM \
                 : "=v"(dst) : "v"(voff), "s"(pn))

#define ISSUE_W8(X) do { \
    ISS(X##b[0], vb, 0);    ISS(X##l1[0], v1, 0);    ISS(X##l3[0], v3, 0); \
    ISS(X##b[1], vb, 512);  ISS(X##l1[1], v1, 512);  ISS(X##l3[1], v3, 512); \
    ISS(X##b[2], vb, 1024); ISS(X##l1[2], v1, 1024); ISS(X##l3[2], v3, 1024); \
    ISS(X##b[3], vb, 1536); ISS(X##l1[3], v1, 1536); ISS(X##l3[3], v3, 1536); \
    ISS(X##b[4], vb, 2048); ISS(X##l1[4], v1, 2048); ISS(X##l3[4], v3, 2048); \
    ISS(X##b[5], vb, 2560); ISS(X##l1[5], v1, 2560); ISS(X##l3[5], v3, 2560); \
    ISS(X##b[6], vb, 3072); ISS(X##l1[6], v1, 3072); ISS(X##l3[6], v3, 3072); \
    ISS(X##b[7], vb, 3584); ISS(X##l1[7], v1, 3584); ISS(X##l3[7], v3, 3584); \
    pn += 8 * 128; \
} while (0)

#define ISSUE_W7(X) do { \
    ISS(X##b[0], vb, 0);    ISS(X##l1[0], v1, 0);    ISS(X##l3[0], v3, 0); \
    ISS(X##b[1], vb, 512);  ISS(X##l1[1], v1, 512);  ISS(X##l3[1], v3, 512); \
    ISS(X##b[2], vb, 1024); ISS(X##l1[2], v1, 1024); ISS(X##l3[2], v3, 1024); \
    ISS(X##b[3], vb, 1536); ISS(X##l1[3], v1, 1536); ISS(X##l3[3], v3, 1536); \
    ISS(X##b[4], vb, 2048); ISS(X##l1[4], v1, 2048); ISS(X##l3[4], v3, 2048); \
    ISS(X##b[5], vb, 2560); ISS(X##l1[5], v1, 2560); ISS(X##l3[5], v3, 2560); \
    ISS(X##b[6], vb, 3072); ISS(X##l1[6], v1, 3072); ISS(X##l3[6], v3, 3072); \
} while (0)

// ---- one CTC step (identical math to the verified round-3 kernel) ----
#define STEP(PB_, P1_, P3_) do { \
    const float pbe = (PB_) + EPSF; \
    const float rpb = f_rcp(pbe); \
    const float q1  = ((P1_) + EPSF) * rpb; \
    const float q3  = ((P3_) + EPSF) * rpb; \
    const float n3  = wave_shr1_f(u3); \
    const float t1  = fmaf(m1, n3, u0 + u1); \
    const float t3  = fmaf(m3, u1, u2 + u3); \
    u4 = u4 + u3; \
    u3 = t3 * q3; \
    u2 = u2 + u1; \
    u1 = t1 * q1; \
    u0 = u0 + n3; \
    O += __logf(pbe); \
} while (0)

#define APPLY() do { \
    const float rm_ = f_rcp(m_carry); \
    u0 *= rm_; u1 *= rm_; u2 *= rm_; u3 *= rm_; u4 *= rm_; \
    O += __logf(m_carry); \
} while (0)

#define SNAP() do { \
    m_carry = wave_max64(fmaxf(fmaxf(u0, u1), fmaxf(u2, fmaxf(u3, u4)))); \
} while (0)

#define STEPK(X, k) STEP(X##b[k], X##l1[k], X##l3[k])
#define CONSUME_W8(X) do { \
    STEPK(X,0); STEPK(X,1); APPLY(); \
    STEPK(X,2); STEPK(X,3); STEPK(X,4); STEPK(X,5); STEPK(X,6); STEPK(X,7); \
    SNAP(); \
} while (0)
#define CONSUME_T7(X) do { \
    STEPK(X,0); STEPK(X,1); APPLY(); \
    STEPK(X,2); STEPK(X,3); STEPK(X,4); STEPK(X,5); STEPK(X,6); \
} while (0)

// Specialized T=512, C=128, U=128. One wave per batch row; lane l owns states
// 4l..4l+3 (+256 on lane 63). Linear-domain Rabiner-scaled recursion.
__global__ __launch_bounds__(64, 1) void ctc_pipe512(
        const int* __restrict__ y_true, const float* __restrict__ y_pred,
        float* __restrict__ out) {
    const int b    = blockIdx.x;
    const int lane = threadIdx.x;
    const float* __restrict__ yp = y_pred + (size_t)b * (512 * 128);

    const int2 lc = ((const int2*)(y_true + (size_t)b * 128))[lane];
    const int c1 = lc.x, c3 = lc.y;
    const int cp = __builtin_amdgcn_update_dpp(0, c3, 0x138, 0xF, 0xF, false);
    const float m1 = (lane > 0 && c1 != cp) ? 1.f : 0.f;
    const float m3 = (c3 != c1) ? 1.f : 0.f;

    float u0, u1, u2 = 0.f, u3 = 0.f, u4 = 0.f;
    {
        const float pvb = yp[127];         // blank prob at t=0
        const float pv1 = yp[c1];
        u0 = (lane == 0) ? pvb + EPSF : 0.f;
        u1 = (lane == 0) ? pv1 + EPSF : 0.f;
    }
    float O = 0.f, m_carry = 1.0f;

    const int vb = 127 * 4;        // blank voffset (uniform)
    const int v1 = c1 * 4;
    const int v3 = c3 * 4;
    const float* pn = yp + 128;    // row 1

    WAITV(0);   // drain init loads: explicit vmcnt counting starts at 0

    float Ab[8], Al1[8], Al3[8];
    float Bb[8], Bl1[8], Bl3[8];
    float Cb[8], Cl1[8], Cl3[8];

    ISSUE_W8(A);   // W0: rows 1..8
    ISSUE_W8(B);   // W1: rows 9..16

    for (int j = 0; j < 20; ++j) {
        ISSUE_W8(C);  WAITV(48);  CONSUME_W8(A);   // consume W(3j),   issue W(3j+2)
        ISSUE_W8(A);  WAITV(48);  CONSUME_W8(B);   // consume W(3j+1), issue W(3j+3)
        ISSUE_W8(B);  WAITV(48);  CONSUME_W8(C);   // consume W(3j+2), issue W(3j+4)
    }
    // consumed W0..W59; A=W60, B=W61 in flight; pn at row 497
    ISSUE_W8(C);       // W62: rows 497..504
    WAITV(48);  CONSUME_W8(A);     // W60
    ISSUE_W7(A);       // tail: rows 505..511 (21 loads)
    WAITV(45);  CONSUME_W8(B);     // W61
    WAITV(21);  CONSUME_W8(C);     // W62
    WAITV(0);   CONSUME_T7(A);     // steps 505..511

    if (lane == 63) out[b] = -(O + __logf(u3 + u4));
}

// ---- generic fallback (verified round-3 kernel) for other shapes ----
__global__ __launch_bounds__(64, 1) void ctc_scan_generic(
        const int* __restrict__ y_true, const float* __restrict__ y_pred,
        float* __restrict__ out, int T, int C, int U) {
    const int b    = blockIdx.x;
    const int lane = threadIdx.x;
    const int blank = C - 1;
    const float* __restrict__ yp = y_pred + (size_t)b * T * C;

    const int2 lc = ((const int2*)(y_true + (size_t)b * U))[lane];
    const int c1 = lc.x, c3 = lc.y;
    const int cp = __builtin_amdgcn_update_dpp(0, c3, 0x138, 0xF, 0xF, false);
    const float m1 = (lane > 0 && c1 != cp) ? 1.f : 0.f;
    const float m3 = (c3 != c1) ? 1.f : 0.f;

    float u0, u1, u2 = 0.f, u3 = 0.f, u4 = 0.f;
    u0 = (lane == 0) ? yp[blank] + EPSF : 0.f;
    u1 = (lane == 0) ? yp[c1] + EPSF : 0.f;
    float O = 0.f, m_carry = 1.0f;
    int kren = 0;

    for (int t = 1; t < T; ++t) {
        const float* row = yp + (size_t)t * C;
        STEP(row[blank], row[c1], row[c3]);
        if (++kren == 8) { SNAP(); APPLY(); kren = 0; }
    }
    if (lane == 63) out[b] = -(O + __logf(u3 + u4));
}

extern "C" void kernel_launch(void* const* d_in, const int* in_sizes, int n_in,
                              void* d_out, int out_size, void* d_ws, size_t ws_size,
                              hipStream_t stream) {
    const int*   y_true = (const int*)d_in[0];
    const float* y_pred = (const float*)d_in[1];
    float*       out    = (float*)d_out;

    const int B = out_size;                 // 256
    const int U = in_sizes[0] / B;          // 128
    const int C = 128;                      // classes incl. blank
    const int T = in_sizes[1] / (B * C);    // 512

    if (T == 512 && C == 128 && U == 128) {
        ctc_pipe512<<<B, 64, 0, stream>>>(y_true, y_pred, out);
    } else {
        ctc_scan_generic<<<B, 64, 0, stream>>>(y_true, y_pred, out, T, C, U);
    }
}